// Round 6
// baseline (1326.809 us; speedup 1.0000x reference)
//
#include <hip/hip_runtime.h>

typedef float f4 __attribute__((ext_vector_type(4)));

#define LENT 998
#define NSAMP 63872   // 64 * 998

// ---------------------------------------------------------------------------
// Full-fp32 fused MLP+JVP. Grid = (250, 8): blockIdx.x covers 4 timesteps
// (one per wave), blockIdx.y = latent l. Lane = sample (batch row) — each
// thread computes its entire sample privately; weights are LDS broadcast.
// Rationale (R5): bf16 MFMA tangent path gave logdet absmax 10.25 — log|J|
// needs ~1e-5 relative J accuracy and fp32-accurate lrelu masks; no fp32
// MFMA on CDNA4 -> VALU fp32 everywhere.
// ---------------------------------------------------------------------------
__global__ __launch_bounds__(256, 2) void mlp_fp32(
    const float* __restrict__ xp,  const float* __restrict__ embp,
    const float* __restrict__ gW0, const float* __restrict__ gb0,
    const float* __restrict__ gW1, const float* __restrict__ gb1,
    const float* __restrict__ gW2, const float* __restrict__ gb2,
    const float* __restrict__ gW3, const float* __restrict__ gb3,
    float* __restrict__ out)
{
    __shared__ float sW1t[4096];          // W1 transposed: sW1t[k*64+j] = W1[j][k]
    __shared__ float sW2t[4096];
    __shared__ float sE0[4][64];          // per-wave E0 (depends on t)
    __shared__ float sw0c[64], sb1[64], sb2[64], sw3[64];

    const int tid  = threadIdx.x;
    const int wave = tid >> 6, lane = tid & 63;
    const int l    = blockIdx.y;
    const int t    = blockIdx.x * 4 + wave;        // 250*4 = 1000 >= 998
    const int tc   = t < LENT ? t : LENT - 1;      // clamp for safe loads
    const bool active = (t < LENT);

    // ---- stage W1/W2 transposed (k-major) + small vectors ----
#pragma unroll
    for (int i = 0; i < 4; ++i) {
        int base = i * 1024 + tid * 4;             // 4 elements of row j
        f4 a = *(const f4*)(gW1 + l * 4096 + base);
        f4 b = *(const f4*)(gW2 + l * 4096 + base);
        int j = base >> 6, k = base & 63;          // k..k+3 same row j
        sW1t[(k + 0) * 64 + j] = a.x; sW1t[(k + 1) * 64 + j] = a.y;
        sW1t[(k + 2) * 64 + j] = a.z; sW1t[(k + 3) * 64 + j] = a.w;
        sW2t[(k + 0) * 64 + j] = b.x; sW2t[(k + 1) * 64 + j] = b.y;
        sW2t[(k + 2) * 64 + j] = b.z; sW2t[(k + 3) * 64 + j] = b.w;
    }
    if (tid < 64) {
        sw0c[tid] = gW0[(l * 64 + tid) * 17 + 16]; // dz/dx column of W0
        sb1[tid]  = gb1[l * 64 + tid];
        sb2[tid]  = gb2[l * 64 + tid];
        sw3[tid]  = gW3[l * 64 + tid];
    }
    __syncthreads();

    // ---- E0[j] = b0 + W0[:, :16] @ emb[t+2]  (per wave; lane = feature j) ----
    {
        const float* r = gW0 + (size_t)(l * 64 + lane) * 17;
        const float* e = embp + (tc + 2) * 16;
        float acc = gb0[l * 64 + lane];
#pragma unroll
        for (int q = 0; q < 16; ++q) acc = fmaf(r[q], e[q], acc);
        sE0[wave][lane] = acc;
    }
    __syncthreads();

    const int b   = lane;                          // sample batch row
    const float xv = xp[(size_t)(b * 1000 + tc + 2) * 8 + l];
    const float b3 = gb3[l];

    // ---- layer 0 + layer 1 (j-chunks of 16; k dynamic; h0 rebuilt per k) ----
    float h1[64], dh1[64];
#pragma unroll
    for (int jc = 0; jc < 4; ++jc) {
        float acc[16], dacc[16];
#pragma unroll
        for (int jj = 0; jj < 16; ++jj) { acc[jj] = sb1[jc * 16 + jj]; dacc[jj] = 0.f; }
#pragma unroll 4
        for (int k = 0; k < 64; ++k) {
            float e0k = sE0[wave][k];
            float w0k = sw0c[k];
            float p   = fmaf(w0k, xv, e0k);
            float h0k = fmaxf(p, 0.2f * p);                 // leaky_relu
            float d0k = (p >= 0.f) ? w0k : 0.2f * w0k;      // mask * dz
            const float* wr = &sW1t[k * 64 + jc * 16];
#pragma unroll
            for (int jj = 0; jj < 16; ++jj) {
                float w = wr[jj];
                acc[jj]  = fmaf(w, h0k, acc[jj]);
                dacc[jj] = fmaf(w, d0k, dacc[jj]);
            }
        }
#pragma unroll
        for (int jj = 0; jj < 16; ++jj) {
            float p = acc[jj];
            h1[jc * 16 + jj]  = fmaxf(p, 0.2f * p);
            dh1[jc * 16 + jj] = ((p >= 0.f) ? 1.f : 0.2f) * dacc[jj];
        }
    }

    // ---- layer 2 (j-quarters to cap registers; k fully unrolled: h1 in regs)
    //      + layer 3 dot fused into the quarter epilogue ----
    float rs = b3, js = 0.f;
#pragma unroll
    for (int q = 0; q < 4; ++q) {
        float acc[16], dacc[16];
#pragma unroll
        for (int jj = 0; jj < 16; ++jj) { acc[jj] = sb2[q * 16 + jj]; dacc[jj] = 0.f; }
#pragma unroll
        for (int k = 0; k < 64; ++k) {
            const float* wr = &sW2t[k * 64 + q * 16];
            float hk = h1[k], dk = dh1[k];
#pragma unroll
            for (int jj = 0; jj < 16; ++jj) {
                float w = wr[jj];
                acc[jj]  = fmaf(w, hk, acc[jj]);
                dacc[jj] = fmaf(w, dk, dacc[jj]);
            }
        }
#pragma unroll
        for (int jj = 0; jj < 16; ++jj) {
            float p  = acc[jj];
            float w3 = sw3[q * 16 + jj];
            rs = fmaf(w3, fmaxf(p, 0.2f * p), rs);
            js = fmaf(w3, ((p >= 0.f) ? 1.f : 0.2f) * dacc[jj], js);
        }
    }

    if (active) {
        out[(size_t)(b * LENT + t) * 8 + l] = rs;
        atomicAdd(&out[(size_t)NSAMP * 8 + b * LENT + t], __logf(fabsf(js)));
    }
}

extern "C" void kernel_launch(void* const* d_in, const int* in_sizes, int n_in,
                              void* d_out, int out_size, void* d_ws, size_t ws_size,
                              hipStream_t stream) {
    (void)in_sizes; (void)n_in; (void)out_size; (void)d_ws; (void)ws_size;
    // zero the logdet region (accumulated via atomicAdd across the l-grid);
    // d_out is re-poisoned to 0xAA before every timed launch.
    hipMemsetAsync((char*)d_out + (size_t)NSAMP * 8 * sizeof(float), 0,
                   (size_t)NSAMP * sizeof(float), stream);
    mlp_fp32<<<dim3(250, 8), 256, 0, stream>>>(
        (const float*)d_in[0], (const float*)d_in[1],
        (const float*)d_in[2], (const float*)d_in[3],
        (const float*)d_in[4], (const float*)d_in[5],
        (const float*)d_in[6], (const float*)d_in[7],
        (const float*)d_in[8], (const float*)d_in[9],
        (float*)d_out);
}

// Round 7
// 552.471 us; speedup vs baseline: 2.4016x; 2.4016x over previous
//
#include <hip/hip_runtime.h>

typedef float f4 __attribute__((ext_vector_type(4)));

#define LENT 998
#define NSAMP 63872   // 64 * 998
#define WSTR 65       // padded LDS stride for transposed weights (no bank conflicts)

// ---------------------------------------------------------------------------
// Full-fp32 fused MLP+JVP, lane-pair split (R7).
// Grid = (499, 8): blockIdx.x covers 2 timesteps (2 waves each), blockIdx.y = l.
// Each sample (b,t,l) is computed by a LANE PAIR (lane, lane^32): thread owns
// 32 of 64 hidden features -> h1h/dh1h = 64 VGPRs (R6 spilled 128-float
// arrays to scratch: 4.0 GB HBM traffic = the whole 1283 us).
// Pre-activations completed via __shfl_xor(.,32); all array indices static.
// ---------------------------------------------------------------------------
__global__ __launch_bounds__(256, 3) void mlp_fp32(
    const float* __restrict__ xp,  const float* __restrict__ embp,
    const float* __restrict__ gW0, const float* __restrict__ gb0,
    const float* __restrict__ gW1, const float* __restrict__ gb1,
    const float* __restrict__ gW2, const float* __restrict__ gb2,
    const float* __restrict__ gW3, const float* __restrict__ gb3,
    float* __restrict__ out)
{
    __shared__ float sW1t[64 * WSTR];     // sW1t[k*WSTR+j] = W1[j][k]
    __shared__ float sW2t[64 * WSTR];
    __shared__ float sE0[2][64];          // per-t E0 = b0 + W0[:,:16] @ emb
    __shared__ float sw0c[64], sb1[64], sb2[64], sw3[64];

    const int tid  = threadIdx.x;
    const int wave = tid >> 6, lane = tid & 63;
    const int kh   = lane >> 5;           // feature-half owned by this thread
    const int l    = blockIdx.y;
    const int tl   = wave >> 1;           // t within block (0/1)
    const int t    = blockIdx.x * 2 + tl; // 499*2 = 998 exactly
    const int b    = (wave & 1) * 32 + (lane & 31);   // batch row

    // ---- stage W1/W2 transposed (padded stride: conflict-free) ----
    for (int i = tid; i < 1024; i += 256) {
        f4 a = ((const f4*)(gW1 + (size_t)l * 4096))[i];
        f4 c = ((const f4*)(gW2 + (size_t)l * 4096))[i];
        int e = i * 4, j = e >> 6, k = e & 63;
        sW1t[(k + 0) * WSTR + j] = a.x; sW1t[(k + 1) * WSTR + j] = a.y;
        sW1t[(k + 2) * WSTR + j] = a.z; sW1t[(k + 3) * WSTR + j] = a.w;
        sW2t[(k + 0) * WSTR + j] = c.x; sW2t[(k + 1) * WSTR + j] = c.y;
        sW2t[(k + 2) * WSTR + j] = c.z; sW2t[(k + 3) * WSTR + j] = c.w;
    }
    if (tid < 64) {
        sw0c[tid] = gW0[(l * 64 + tid) * 17 + 16];
        sb1[tid]  = gb1[l * 64 + tid];
        sb2[tid]  = gb2[l * 64 + tid];
        sw3[tid]  = gW3[l * 64 + tid];
    }
    if (tid < 128) {                      // E0 for the block's 2 timesteps
        int tt = blockIdx.x * 2 + (tid >> 6), j = tid & 63;
        const float* r = gW0 + (size_t)(l * 64 + j) * 17;
        const float* e = embp + (tt + 2) * 16;
        float acc = gb0[l * 64 + j];
#pragma unroll
        for (int q = 0; q < 16; ++q) acc = fmaf(r[q], e[q], acc);
        sE0[tid >> 6][j] = acc;
    }
    __syncthreads();

    const float xv = xp[(size_t)b * 8000 + (size_t)(t + 2) * 8 + l];

    // ---- layer 0 (recomputed per k) + layer 1, split over k-halves ----
    float h1h[32], dh1h[32];
#pragma unroll
    for (int i = 0; i < 32; ++i) { h1h[i] = 0.f; dh1h[i] = 0.f; }
#pragma unroll
    for (int q = 0; q < 4; ++q) {         // q static: keep-indices static
        float acc[16], dacc[16];
#pragma unroll
        for (int jj = 0; jj < 16; ++jj) { acc[jj] = 0.f; dacc[jj] = 0.f; }
#pragma unroll 8
        for (int kk = 0; kk < 32; ++kk) {
            const int k = kh * 32 + kk;
            float e0k = sE0[tl][k];
            float w0k = sw0c[k];
            float p   = fmaf(w0k, xv, e0k);
            float h0k = fmaxf(p, 0.2f * p);
            float d0k = (p >= 0.f) ? w0k : 0.2f * w0k;
            const float* wr = &sW1t[k * WSTR + q * 16];
#pragma unroll
            for (int jj = 0; jj < 16; ++jj) {
                float w = wr[jj];
                acc[jj]  = fmaf(w, h0k, acc[jj]);
                dacc[jj] = fmaf(w, d0k, dacc[jj]);
            }
        }
        const bool keep = ((q >> 1) == kh);
        const int  base = (q & 1) * 16;
#pragma unroll
        for (int jj = 0; jj < 16; ++jj) {
            float av = acc[jj]  + __shfl_xor(acc[jj], 32, 64);
            float dv = dacc[jj] + __shfl_xor(dacc[jj], 32, 64);
            float p  = av + sb1[q * 16 + jj];
            float hv = fmaxf(p, 0.2f * p);
            float tv = ((p >= 0.f) ? 1.f : 0.2f) * dv;
            h1h[base + jj]  = keep ? hv : h1h[base + jj];
            dh1h[base + jj] = keep ? tv : dh1h[base + jj];
        }
    }

    // ---- layer 2 (thread's feature-half = its k-half) + layer 3 fused ----
    float rs = gb3[l], js = 0.f;
    for (int q = 0; q < 4; ++q) {         // q dynamic: code-size control
        float acc[16], dacc[16];
#pragma unroll
        for (int jj = 0; jj < 16; ++jj) { acc[jj] = 0.f; dacc[jj] = 0.f; }
#pragma unroll
        for (int kk = 0; kk < 32; ++kk) { // full unroll: h1h indices static
            const int k = kh * 32 + kk;
            const float* wr = &sW2t[k * WSTR + q * 16];
            float hk = h1h[kk], dk = dh1h[kk];
#pragma unroll
            for (int jj = 0; jj < 16; ++jj) {
                float w = wr[jj];
                acc[jj]  = fmaf(w, hk, acc[jj]);
                dacc[jj] = fmaf(w, dk, dacc[jj]);
            }
        }
#pragma unroll
        for (int jj = 0; jj < 16; ++jj) {
            float av = acc[jj]  + __shfl_xor(acc[jj], 32, 64);
            float dv = dacc[jj] + __shfl_xor(dacc[jj], 32, 64);
            float p  = av + sb2[q * 16 + jj];
            float w3 = sw3[q * 16 + jj];
            rs = fmaf(w3, fmaxf(p, 0.2f * p), rs);
            js = fmaf(w3, ((p >= 0.f) ? 1.f : 0.2f) * dv, js);
        }
    }

    if (kh == 0) {   // both pair-threads hold identical rs/js; one writes
        out[(size_t)(b * LENT + t) * 8 + l] = rs;
        atomicAdd(&out[(size_t)NSAMP * 8 + b * LENT + t], __logf(fabsf(js)));
    }
}

extern "C" void kernel_launch(void* const* d_in, const int* in_sizes, int n_in,
                              void* d_out, int out_size, void* d_ws, size_t ws_size,
                              hipStream_t stream) {
    (void)in_sizes; (void)n_in; (void)out_size; (void)d_ws; (void)ws_size;
    // zero logdet region (accumulated via atomicAdd across the l-grid)
    hipMemsetAsync((char*)d_out + (size_t)NSAMP * 8 * sizeof(float), 0,
                   (size_t)NSAMP * sizeof(float), stream);
    mlp_fp32<<<dim3(499, 8), 256, 0, stream>>>(
        (const float*)d_in[0], (const float*)d_in[1],
        (const float*)d_in[2], (const float*)d_in[3],
        (const float*)d_in[4], (const float*)d_in[5],
        (const float*)d_in[6], (const float*)d_in[7],
        (const float*)d_in[8], (const float*)d_in[9],
        (float*)d_out);
}

// Round 8
// 378.434 us; speedup vs baseline: 3.5060x; 1.4599x over previous
//
#include <hip/hip_runtime.h>

typedef float f4 __attribute__((ext_vector_type(4)));

#define LENT 998
#define NSAMP 63872   // 64 * 998

// ---------------------------------------------------------------------------
// Full-fp32 fused MLP+JVP, lane-QUAD split (R8).
// Grid = (998, 8): block = one (t, l). 256 threads = 64 samples x 4 lanes.
// Sample owned by lanes {s, s+16, s+32, s+48}; each thread owns 16 of the 64
// hidden features -> max per-thread array = 16 floats (R6/R7 spilled 128/64-
// float arrays to scratch: 4.0/0.97 GB HBM = the entire runtime).
// Both 64x64 GEMVs: 4-step quad rotation (__shfl_xor 16/32/48) against
// row-major LDS weights (straight coalesced staging, conflict-free; reads
// are broadcast-4 b128 with 2-way bank aliasing = free per m136).
// ---------------------------------------------------------------------------
__global__ __launch_bounds__(256, 3) void mlp_fp32(
    const float* __restrict__ xp,  const float* __restrict__ embp,
    const float* __restrict__ gW0, const float* __restrict__ gb0,
    const float* __restrict__ gW1, const float* __restrict__ gb1,
    const float* __restrict__ gW2, const float* __restrict__ gb2,
    const float* __restrict__ gW3, const float* __restrict__ gb3,
    float* __restrict__ out)
{
    __shared__ float sW1[4096];          // row-major [j*64 + k], straight copy
    __shared__ float sW2[4096];
    __shared__ float sE0[64];            // b0 + W0[:,:16] @ emb[t+2]
    __shared__ float sw0c[64], sb1[64], sb2[64], sw3[64];

    const int tid  = threadIdx.x;
    const int wave = tid >> 6, lane = tid & 63;
    const int qd   = lane >> 4, s = lane & 15;   // quad id / sample-in-wave
    const int t    = blockIdx.x, l = blockIdx.y;
    const int b    = wave * 16 + s;              // batch row (64 per block)

    // ---- stage W1/W2: straight coalesced copy, conflict-free b128 ----
    {
        const f4* g1 = (const f4*)(gW1 + (size_t)l * 4096);
        const f4* g2 = (const f4*)(gW2 + (size_t)l * 4096);
        f4* d1 = (f4*)sW1; f4* d2 = (f4*)sW2;
#pragma unroll
        for (int i = 0; i < 4; ++i) {
            d1[i * 256 + tid] = g1[i * 256 + tid];
            d2[i * 256 + tid] = g2[i * 256 + tid];
        }
    }
    if (tid < 64) {
        const float* r = gW0 + (size_t)(l * 64 + tid) * 17;
        const float* e = embp + (t + 2) * 16;
        float acc = gb0[l * 64 + tid];
#pragma unroll
        for (int q = 0; q < 16; ++q) acc = fmaf(r[q], e[q], acc);
        sE0[tid]  = acc;
        sw0c[tid] = r[16];
        sb1[tid]  = gb1[l * 64 + tid];
        sb2[tid]  = gb2[l * 64 + tid];
        sw3[tid]  = gW3[l * 64 + tid];
    }
    __syncthreads();

    const float xv = xp[(size_t)b * 8000 + (size_t)(t + 2) * 8 + l];

    // ---- layer 0: thread's own k-chunk only (16 k) ----
    float h0q[16], d0q[16];
#pragma unroll
    for (int i = 0; i < 16; ++i) {
        const int k = qd * 16 + i;
        float w0 = sw0c[k];
        float p  = fmaf(w0, xv, sE0[k]);
        h0q[i] = fmaxf(p, 0.2f * p);
        d0q[i] = (p >= 0.f) ? w0 : 0.2f * w0;
    }

    // ---- layer 1: o1[j in chunk] = sum_k W1[j][k] h0[k], quad rotation ----
    float acc[16], dacc[16];
#pragma unroll
    for (int jj = 0; jj < 16; ++jj) { acc[jj] = 0.f; dacc[jj] = 0.f; }
#pragma unroll
    for (int r = 0; r < 4; ++r) {
        const int kb = (qd ^ r) * 16;
        float hk[16], dk[16];
#pragma unroll
        for (int i = 0; i < 16; ++i) {
            hk[i] = (r == 0) ? h0q[i] : __shfl_xor(h0q[i], r << 4, 64);
            dk[i] = (r == 0) ? d0q[i] : __shfl_xor(d0q[i], r << 4, 64);
        }
#pragma unroll
        for (int jj = 0; jj < 16; ++jj) {
            const float* wr = &sW1[(qd * 16 + jj) * 64 + kb];
#pragma unroll
            for (int i = 0; i < 16; ++i) {
                float w = wr[i];
                acc[jj]  = fmaf(w, hk[i], acc[jj]);
                dacc[jj] = fmaf(w, dk[i], dacc[jj]);
            }
        }
    }
    float h1q[16], dh1q[16];
#pragma unroll
    for (int jj = 0; jj < 16; ++jj) {
        float p = acc[jj] + sb1[qd * 16 + jj];
        h1q[jj]  = fmaxf(p, 0.2f * p);
        dh1q[jj] = ((p >= 0.f) ? 1.f : 0.2f) * dacc[jj];
    }

    // ---- layer 2: same rotation against W2 ----
#pragma unroll
    for (int jj = 0; jj < 16; ++jj) { acc[jj] = 0.f; dacc[jj] = 0.f; }
#pragma unroll
    for (int r = 0; r < 4; ++r) {
        const int kb = (qd ^ r) * 16;
        float hk[16], dk[16];
#pragma unroll
        for (int i = 0; i < 16; ++i) {
            hk[i] = (r == 0) ? h1q[i]  : __shfl_xor(h1q[i],  r << 4, 64);
            dk[i] = (r == 0) ? dh1q[i] : __shfl_xor(dh1q[i], r << 4, 64);
        }
#pragma unroll
        for (int jj = 0; jj < 16; ++jj) {
            const float* wr = &sW2[(qd * 16 + jj) * 64 + kb];
#pragma unroll
            for (int i = 0; i < 16; ++i) {
                float w = wr[i];
                acc[jj]  = fmaf(w, hk[i], acc[jj]);
                dacc[jj] = fmaf(w, dk[i], dacc[jj]);
            }
        }
    }

    // ---- layer 3: per-thread partial dot + quad butterfly reduce ----
    float rs = 0.f, js = 0.f;
#pragma unroll
    for (int jj = 0; jj < 16; ++jj) {
        float p  = acc[jj] + sb2[qd * 16 + jj];
        float w3 = sw3[qd * 16 + jj];
        rs = fmaf(w3, fmaxf(p, 0.2f * p), rs);
        js = fmaf(w3, ((p >= 0.f) ? 1.f : 0.2f) * dacc[jj], js);
    }
    rs += __shfl_xor(rs, 16, 64); rs += __shfl_xor(rs, 32, 64);
    js += __shfl_xor(js, 16, 64); js += __shfl_xor(js, 32, 64);

    if (qd == 0) {
        out[(size_t)(b * LENT + t) * 8 + l] = rs + gb3[l];
        atomicAdd(&out[(size_t)NSAMP * 8 + b * LENT + t], __logf(fabsf(js)));
    }
}

extern "C" void kernel_launch(void* const* d_in, const int* in_sizes, int n_in,
                              void* d_out, int out_size, void* d_ws, size_t ws_size,
                              hipStream_t stream) {
    (void)in_sizes; (void)n_in; (void)out_size; (void)d_ws; (void)ws_size;
    // zero logdet region (accumulated via atomicAdd across the l-grid)
    hipMemsetAsync((char*)d_out + (size_t)NSAMP * 8 * sizeof(float), 0,
                   (size_t)NSAMP * sizeof(float), stream);
    mlp_fp32<<<dim3(LENT, 8), 256, 0, stream>>>(
        (const float*)d_in[0], (const float*)d_in[1],
        (const float*)d_in[2], (const float*)d_in[3],
        (const float*)d_in[4], (const float*)d_in[5],
        (const float*)d_in[6], (const float*)d_in[7],
        (const float*)d_in[8], (const float*)d_in[9],
        (float*)d_out);
}

// Round 9
// 338.791 us; speedup vs baseline: 3.9163x; 1.1170x over previous
//
#include <hip/hip_runtime.h>

typedef float f4 __attribute__((ext_vector_type(4)));

#define LENT 998
#define NSAMP 63872   // 64 * 998
#define WS 68         // k-major LDS stride: 16B-aligned rows (272B), 2-way bank alias on reads (free)

// ---------------------------------------------------------------------------
// Full-fp32 fused MLP+JVP, quad-split + M=2 register blocking (R9).
// R8 was LDS-throughput bound: 512 ds_read_b128/thread/l x 12cyc on the
// per-CU LDS pipe = 319 us model vs 348 measured. Two timesteps per thread
// amortize each weight read over 16 FMAs (2 samples x 2 paths x 4/b128).
// Layer-0 is rebuilt on the fly inside the L1 k-loop (no h0 arrays, no L1
// shuffles); only L2 uses the quad rotation. l-loop in-block: logdet in
// registers, no atomics, no memset, single dispatch.
// ---------------------------------------------------------------------------
__global__ __launch_bounds__(256, 2) void mlp_fp32(
    const float* __restrict__ xp,  const float* __restrict__ embp,
    const float* __restrict__ gW0, const float* __restrict__ gb0,
    const float* __restrict__ gW1, const float* __restrict__ gb1,
    const float* __restrict__ gW2, const float* __restrict__ gb2,
    const float* __restrict__ gW3, const float* __restrict__ gb3,
    float* __restrict__ out)
{
    __shared__ float sW1t[64 * WS];      // sW1t[k*WS + j] = W1[j][k]
    __shared__ float sW2t[64 * WS];
    __shared__ float sE0[2][64];         // E0 per local timestep
    __shared__ float sw0c[64], sb1[64], sb2[64], sw3[64];

    const int tid  = threadIdx.x;
    const int wave = tid >> 6, lane = tid & 63;
    const int qd   = lane >> 4, s = lane & 15;
    const int t0   = blockIdx.x * 2;     // 499*2 = 998 exactly
    const int b    = wave * 16 + s;

    float ld0 = 0.f, ld1 = 0.f;

    for (int l = 0; l < 8; ++l) {
        __syncthreads();                 // prior-iter LDS reads done
        {   // stage W1/W2 k-major; write conflicts ~8-way on 8 insts (negligible)
            const f4* g1 = (const f4*)(gW1 + (size_t)l * 4096);
            const f4* g2 = (const f4*)(gW2 + (size_t)l * 4096);
#pragma unroll
            for (int i = 0; i < 4; ++i) {
                int idx = i * 256 + tid;
                f4 a = g1[idx], c = g2[idx];
                int e = idx * 4, j = e >> 6, k = e & 63;
                sW1t[(k + 0) * WS + j] = a.x; sW1t[(k + 1) * WS + j] = a.y;
                sW1t[(k + 2) * WS + j] = a.z; sW1t[(k + 3) * WS + j] = a.w;
                sW2t[(k + 0) * WS + j] = c.x; sW2t[(k + 1) * WS + j] = c.y;
                sW2t[(k + 2) * WS + j] = c.z; sW2t[(k + 3) * WS + j] = c.w;
            }
        }
        if (tid < 128) {                 // E0 for both timesteps; w0c
            int tt = tid >> 6, j = tid & 63;
            const float* r = gW0 + (size_t)(l * 64 + j) * 17;
            const float* e = embp + (t0 + tt + 2) * 16;
            float acc = gb0[l * 64 + j];
#pragma unroll
            for (int q = 0; q < 16; ++q) acc = fmaf(r[q], e[q], acc);
            sE0[tt][j] = acc;
            if (tt == 0) sw0c[j] = r[16];
        } else if (tid < 192) {
            int j = tid - 128;
            sb1[j] = gb1[l * 64 + j];
            sb2[j] = gb2[l * 64 + j];
            sw3[j] = gW3[l * 64 + j];
        }
        __syncthreads();

        const float xv0 = xp[((size_t)b * 1000 + t0 + 2) * 8 + l];
        const float xv1 = xp[((size_t)b * 1000 + t0 + 3) * 8 + l];

        // ---- layer 1 with on-the-fly layer 0 (no shuffles, no h0 arrays) ----
        float a0[16], d0[16], a1[16], d1v[16];
#pragma unroll
        for (int jj = 0; jj < 16; ++jj) { a0[jj] = 0.f; d0[jj] = 0.f; a1[jj] = 0.f; d1v[jj] = 0.f; }
#pragma unroll 4
        for (int k4 = 0; k4 < 16; ++k4) {
            f4 e0v = *(const f4*)&sE0[0][k4 * 4];
            f4 e1v = *(const f4*)&sE0[1][k4 * 4];
            f4 w0v = *(const f4*)&sw0c[k4 * 4];
#pragma unroll
            for (int ki = 0; ki < 4; ++ki) {
                const int k = k4 * 4 + ki;
                float w0 = w0v[ki];
                float p0 = fmaf(w0, xv0, e0v[ki]);
                float p1 = fmaf(w0, xv1, e1v[ki]);
                float h00 = fmaxf(p0, 0.2f * p0);
                float h01 = fmaxf(p1, 0.2f * p1);
                float d00 = (p0 >= 0.f) ? w0 : 0.2f * w0;
                float d01 = (p1 >= 0.f) ? w0 : 0.2f * w0;
                const float* wr = &sW1t[k * WS + qd * 16];
#pragma unroll
                for (int jj = 0; jj < 16; ++jj) {
                    float w = wr[jj];
                    a0[jj]  = fmaf(w, h00, a0[jj]);
                    d0[jj]  = fmaf(w, d00, d0[jj]);
                    a1[jj]  = fmaf(w, h01, a1[jj]);
                    d1v[jj] = fmaf(w, d01, d1v[jj]);
                }
            }
        }
        // epilogue 1 -> h1 (quad-distributed)
        float h1a[16], t1a[16], h1b[16], t1b[16];
#pragma unroll
        for (int jj = 0; jj < 16; ++jj) {
            float bb = sb1[qd * 16 + jj];
            float p = a0[jj] + bb;
            h1a[jj] = fmaxf(p, 0.2f * p);
            t1a[jj] = ((p >= 0.f) ? 1.f : 0.2f) * d0[jj];
            float q = a1[jj] + bb;
            h1b[jj] = fmaxf(q, 0.2f * q);
            t1b[jj] = ((q >= 0.f) ? 1.f : 0.2f) * d1v[jj];
        }

        // ---- layer 2: quad rotation ----
#pragma unroll
        for (int jj = 0; jj < 16; ++jj) { a0[jj] = 0.f; d0[jj] = 0.f; a1[jj] = 0.f; d1v[jj] = 0.f; }
#pragma unroll
        for (int r = 0; r < 4; ++r) {
#pragma unroll
            for (int i = 0; i < 16; ++i) {
                float hs0 = (r == 0) ? h1a[i] : __shfl_xor(h1a[i], r << 4, 64);
                float ts0 = (r == 0) ? t1a[i] : __shfl_xor(t1a[i], r << 4, 64);
                float hs1 = (r == 0) ? h1b[i] : __shfl_xor(h1b[i], r << 4, 64);
                float ts1 = (r == 0) ? t1b[i] : __shfl_xor(t1b[i], r << 4, 64);
                const int k = ((qd ^ r) << 4) + i;
                const float* wr = &sW2t[k * WS + qd * 16];
#pragma unroll
                for (int jj = 0; jj < 16; ++jj) {
                    float w = wr[jj];
                    a0[jj]  = fmaf(w, hs0, a0[jj]);
                    d0[jj]  = fmaf(w, ts0, d0[jj]);
                    a1[jj]  = fmaf(w, hs1, a1[jj]);
                    d1v[jj] = fmaf(w, ts1, d1v[jj]);
                }
            }
        }

        // ---- layer 3 + quad butterfly + outputs ----
        float rs0 = 0.f, js0 = 0.f, rs1 = 0.f, js1 = 0.f;
#pragma unroll
        for (int jj = 0; jj < 16; ++jj) {
            float bb = sb2[qd * 16 + jj], w3 = sw3[qd * 16 + jj];
            float p = a0[jj] + bb;
            rs0 = fmaf(w3, fmaxf(p, 0.2f * p), rs0);
            js0 = fmaf(w3, ((p >= 0.f) ? 1.f : 0.2f) * d0[jj], js0);
            float q = a1[jj] + bb;
            rs1 = fmaf(w3, fmaxf(q, 0.2f * q), rs1);
            js1 = fmaf(w3, ((q >= 0.f) ? 1.f : 0.2f) * d1v[jj], js1);
        }
        rs0 += __shfl_xor(rs0, 16, 64); rs0 += __shfl_xor(rs0, 32, 64);
        js0 += __shfl_xor(js0, 16, 64); js0 += __shfl_xor(js0, 32, 64);
        rs1 += __shfl_xor(rs1, 16, 64); rs1 += __shfl_xor(rs1, 32, 64);
        js1 += __shfl_xor(js1, 16, 64); js1 += __shfl_xor(js1, 32, 64);
        float b3 = gb3[l];
        if (qd == 0) {
            out[((size_t)b * LENT + t0) * 8 + l]     = rs0 + b3;
            out[((size_t)b * LENT + t0 + 1) * 8 + l] = rs1 + b3;
        }
        ld0 += __logf(fabsf(js0));
        ld1 += __logf(fabsf(js1));
    }

    if (qd == 0) {
        out[(size_t)NSAMP * 8 + (size_t)b * LENT + t0]     = ld0;
        out[(size_t)NSAMP * 8 + (size_t)b * LENT + t0 + 1] = ld1;
    }
}

extern "C" void kernel_launch(void* const* d_in, const int* in_sizes, int n_in,
                              void* d_out, int out_size, void* d_ws, size_t ws_size,
                              hipStream_t stream) {
    (void)in_sizes; (void)n_in; (void)out_size; (void)d_ws; (void)ws_size;
    mlp_fp32<<<dim3(499), 256, 0, stream>>>(
        (const float*)d_in[0], (const float*)d_in[1],
        (const float*)d_in[2], (const float*)d_in[3],
        (const float*)d_in[4], (const float*)d_in[5],
        (const float*)d_in[6], (const float*)d_in[7],
        (const float*)d_in[8], (const float*)d_in[9],
        (float*)d_out);
}